// Round 1
// baseline (291.221 us; speedup 1.0000x reference)
//
#include <hip/hip_runtime.h>

#define SEQ 512
#define BATCH 32768
#define PF 16   // prefetch depth (iterations of input held in registers)

// One thread per batch chain. The recurrence is serial in t, but the input
// stream (ratings) is state-independent, so we prefetch PF iterations ahead
// to keep enough reads in flight (only 2 waves/CU -> MLP must come from ILP).
__global__ __launch_bounds__(128, 1) void sm2_scan_kernel(
    const float2* __restrict__ in,   // (SEQ, BATCH, 2) as float2
    const float* __restrict__ w,     // 6 params
    float* __restrict__ out)         // outputs (SEQ,BATCH,3) then final (BATCH,3)
{
    const int b = blockIdx.x * blockDim.x + threadIdx.x;

    const float w0 = w[0], w1 = w[1], w2 = w[2];
    const float w3 = w[3], w4 = w[4], w5 = w[5];

    // state0: ivl=0, ef=w2, reps=0
    float ivl  = 0.0f;
    float ef   = w2;
    float reps = 0.0f;

    const float2* __restrict__ ip = in + b;
    float* __restrict__ op = out + (size_t)b * 3;
    const size_t ostride = (size_t)BATCH * 3;   // floats per t-slice

    // prime the prefetch pipeline
    float2 buf[PF];
#pragma unroll
    for (int i = 0; i < PF; ++i) buf[i] = ip[(size_t)i * BATCH];

    for (int t0 = 0; t0 < SEQ; t0 += PF) {
        float2 nxt[PF];
        const bool more = (t0 + PF) < SEQ;
        if (more) {
#pragma unroll
            for (int i = 0; i < PF; ++i)
                nxt[i] = ip[(size_t)(t0 + PF + i) * BATCH];
        }

#pragma unroll
        for (int i = 0; i < PF; ++i) {
            const float r = buf[i].y;            // rating in {0,1,2,3}
            const bool success = r > 1.0f;

            // new_reps = success ? reps+1 : 1
            reps = success ? (reps + 1.0f) : 1.0f;

            // new_ivl = reps==1 ? w0 : reps==2 ? w1 : ivl*ef   (old ef!)
            float niv = (reps == 1.0f) ? w0
                       : ((reps == 2.0f) ? w1 : (ivl * ef));

            // new_ef = ef - w3*(q-w4)^2 + w5,  q = r+1
            const float q  = r + 1.0f;
            const float dq = q - w4;
            const float nef = ef - w3 * (dq * dq) + w5;

            ivl = fminf(fmaxf(niv, 0.01f), 36500.0f);
            ef  = fminf(fmaxf(nef, 1.3f), 10.0f);

            float* o = op + (size_t)(t0 + i) * ostride;
            o[0] = ivl;
            o[1] = ef;
            o[2] = reps;
        }

        if (more) {
#pragma unroll
            for (int i = 0; i < PF; ++i) buf[i] = nxt[i];
        }
    }

    // final_state appended after the (SEQ,BATCH,3) outputs
    float* f = out + (size_t)SEQ * ostride + (size_t)b * 3;
    f[0] = ivl;
    f[1] = ef;
    f[2] = reps;
}

extern "C" void kernel_launch(void* const* d_in, const int* in_sizes, int n_in,
                              void* d_out, int out_size, void* d_ws, size_t ws_size,
                              hipStream_t stream) {
    const float2* in = (const float2*)d_in[0];
    const float* w   = (const float*)d_in[1];
    float* out       = (float*)d_out;

    dim3 block(128);                 // 2 waves/block, 256 blocks -> 1 block/CU
    dim3 grid(BATCH / 128);
    sm2_scan_kernel<<<grid, block, 0, stream>>>(in, w, out);
}